// Round 8
// baseline (125.866 us; speedup 1.0000x reference)
//
#include <hip/hip_runtime.h>

typedef __attribute__((ext_vector_type(8))) short bf16x8;
typedef __attribute__((ext_vector_type(4))) float f32x4;
typedef __attribute__((ext_vector_type(8))) unsigned short u16x8;

#define BB 32
#define NN 1024
#define MM 256
#define HH 128

__device__ __forceinline__ unsigned short f2bf(float f) {
  union { float f; unsigned int u; } c; c.f = f;
  unsigned int u = c.u + 0x7fffu + ((c.u >> 16) & 1u);  // RNE
  return (unsigned short)(u >> 16);
}

// native packed f32x2 -> bf16x2 (RNE, 1 instr) — verified r6/r7
__device__ __forceinline__ unsigned int cvtpk(float lo, float hi) {
  unsigned int r;
  asm("v_cvt_pk_bf16_f32 %0, %1, %2" : "=v"(r) : "v"(lo), "v"(hi));
  return r;
}

// volatile global load: cannot be sunk past the explicit vmcnt wait
__device__ __forceinline__ float4 gload_f4(const float* p) {
  float4 r;
  asm volatile("global_load_dwordx4 %0, %1, off" : "=v"(r) : "v"(p) : "memory");
  return r;
}

typedef __attribute__((address_space(3))) unsigned int as3_u32;
typedef const __attribute__((address_space(1))) unsigned int as1_u32;
__device__ __forceinline__ void gl_lds16(const void* g, void* l) {
  __builtin_amdgcn_global_load_lds((as1_u32*)g, (as3_u32*)l, 16, 0, 0);
}

// ---------------- h transpose: h[B][N][M] f32 -> hT[B][M][N] bf16 ----------------
__global__ __launch_bounds__(256)
void k_transpose_h(const float* __restrict__ hg, unsigned short* __restrict__ hTg) {
  __shared__ unsigned short tile[64][65];
  int bid = blockIdx.x;
  int b = bid >> 6;
  int t = bid & 63;
  int k0 = (t >> 2) << 6;
  int m0 = (t & 3) << 6;
  int tt = threadIdx.x;
  {
    int r = tt >> 2;
    int cg = (tt & 3) << 4;
    const float* src = hg + (((size_t)b * NN + k0 + r) * MM + m0 + cg);
#pragma unroll
    for (int i = 0; i < 4; ++i) {
      float4 v = reinterpret_cast<const float4*>(src)[i];
      tile[r][cg + i * 4 + 0] = f2bf(v.x);
      tile[r][cg + i * 4 + 1] = f2bf(v.y);
      tile[r][cg + i * 4 + 2] = f2bf(v.z);
      tile[r][cg + i * 4 + 3] = f2bf(v.w);
    }
  }
  __syncthreads();
  {
    int mr = tt >> 2;
    int kc = (tt & 3) << 4;
    alignas(16) unsigned short tmp[16];
#pragma unroll
    for (int i = 0; i < 16; ++i) tmp[i] = tile[kc + i][mr];
    unsigned short* dst = hTg + (((size_t)b * MM + m0 + mr) * NN + k0 + kc);
    *reinterpret_cast<u16x8*>(dst)     = *reinterpret_cast<u16x8*>(tmp);
    *reinterpret_cast<u16x8*>(dst + 8) = *reinterpret_cast<u16x8*>(tmp + 8);
  }
}

// ------------- W transposes -------------
__global__ __launch_bounds__(256)
void k_transpose_w(const float* __restrict__ W1, const float* __restrict__ W2,
                   unsigned short* __restrict__ W1T, unsigned short* __restrict__ W2T) {
  int idx = blockIdx.x * 256 + threadIdx.x;
  if (idx < MM * HH) {
    int hc = idx >> 8;
    int m  = idx & 255;
    W1T[idx] = f2bf(W1[m * HH + hc]);
  } else {
    int j = idx - MM * HH;
    int m  = j >> 7;
    int hd = j & 127;
    W2T[j] = f2bf(W2[hd * MM + m]);
  }
}

// ---------------- fused main ----------------
// 1024 blocks x 256 threads (4 waves col-split). Block tile 32 rows x 256 cols.
// Goal: 4 blocks/CU = 16 waves/CU in 4 INDEPENDENT barrier groups (every prior
// round had 8 lockstep waves/CU; stalls were fully exposed).
// Phase 1 (32 K-steps of 32): A via volatile-asm reg loads -> cvt -> LDS dbuf;
// H via global_load_lds dbuf; one lgkm-only barrier per step; vmcnt(0) after
// consume. LDS layouts are k-major subtiled ([chunk][row/col]) => 2-way bank
// access (free), no XOR needed on H so gl_lds dest is linear (rule 21).
// LDS map: A0[0,2K) A1[2K,4K) H0[4K,20K) H1[20K,36K)  (36864 B total)
//          phase2 alias: Kld[0,16K); phase3 alias: Cld[0,8K).
#define AB0 0
#define AB1 2048
#define HB0 4096
#define HB1 20480
#define KLD 0
#define CLD 0

#define PIPE_BARRIER() do { \
  asm volatile("s_waitcnt lgkmcnt(0)" ::: "memory"); \
  __builtin_amdgcn_s_barrier(); \
  asm volatile("" ::: "memory"); } while (0)

#define VMWAIT0() do { \
  asm volatile("s_waitcnt vmcnt(0)" ::: "memory"); \
  __builtin_amdgcn_sched_barrier(0); } while (0)

__global__ __launch_bounds__(256, 4)
void k_fused(const float* __restrict__ Ag, const float* __restrict__ hg,
             const unsigned short* __restrict__ hTg,
             const unsigned short* __restrict__ W1Tg,
             const unsigned short* __restrict__ W2Tg,
             const float* __restrict__ b1g, const float* __restrict__ b2g,
             float* __restrict__ outg) {
  __shared__ __align__(16) char smem[36864];
  __shared__ float smax[32];

  const int tid  = threadIdx.x;
  const int lane = tid & 63;
  const int wid  = tid >> 6;       // 0..3 (col quarter)
  const int l15  = lane & 15;
  const int lg   = lane >> 4;      // 0..3
  const int wcol = wid << 6;       // 0,64,128,192

  const int bid = blockIdx.x;
  const int b   = bid & 31;        // batch-b blocks all share bid%8 -> same XCD L2
  const int r0  = (bid >> 5) << 5; // 32 row-blocks of 32

  const float* Ab = Ag + ((size_t)b * NN + r0) * NN;
  const unsigned short* hTb = hTg + (size_t)b * MM * NN;

  // ---- A staging: thread -> (row 0..31, k-quad 0..7). 1 float4 per step. ----
  const int arow = tid >> 3;          // 0..31
  const int akq  = tid & 7;           // k-quad (4 floats)
  const int achk = akq >> 1;          // bf16 16B chunk 0..3
  const int ahlf = akq & 1;           // which 8B half of the chunk
  const float* Asrc = Ab + (size_t)arow * NN + (akq << 2);
  // LDS byte offset for this thread's 8B of chunk data ([chunk][row^] layout)
  const int awb = (achk << 9) + (((arow ^ (achk << 2))) << 4) + (ahlf << 3);

  // ---- H staging: gl_lds, layout [chunk 0..3][col 0..255] 16B slots ----
  const unsigned short* baseH[4];
#pragma unroll
  for (int i = 0; i < 4; ++i) baseH[i] = hTb + (size_t)tid * NN + i * 8;
  const int ldsW = wid << 10;         // wave-uniform base (64 lanes x 16B)

#define STAGE_H(K0, HB)                                                     \
  do {                                                                      \
    _Pragma("unroll")                                                       \
    for (int i = 0; i < 4; ++i)                                             \
      gl_lds16(baseH[i] + (K0), smem + (HB) + ldsW + i * 4096);             \
  } while (0)

  float4 rA;
#define ISSUE_A(K0) do { rA = gload_f4(Asrc + (K0)); } while (0)

  float pmax = -1e30f;
#define CVTWR(AB)                                                           \
  do {                                                                      \
    pmax = fmaxf(pmax, fmaxf(fmaxf(rA.x, rA.y), fmaxf(rA.z, rA.w)));        \
    uint2 q = make_uint2(cvtpk(rA.x, rA.y), cvtpk(rA.z, rA.w));             \
    *reinterpret_cast<uint2*>(smem + (AB) + awb) = q;                       \
  } while (0)

  f32x4 acc[2][4];
#pragma unroll
  for (int m = 0; m < 2; ++m)
#pragma unroll
    for (int n = 0; n < 4; ++n) acc[m][n] = f32x4{0.f, 0.f, 0.f, 0.f};

#define CONS(AB, HB)                                                        \
  do {                                                                      \
    bf16x8 af[2], bh[4];                                                    \
    _Pragma("unroll")                                                       \
    for (int m = 0; m < 2; ++m) {                                           \
      int row = (m << 4) + l15;                                             \
      af[m] = *reinterpret_cast<const bf16x8*>(                             \
          smem + (AB) + (lg << 9) + (((row ^ (lg << 2))) << 4));            \
    }                                                                       \
    _Pragma("unroll")                                                       \
    for (int n = 0; n < 4; ++n) {                                           \
      int col = wcol + (n << 4) + l15;                                      \
      bh[n] = *reinterpret_cast<const bf16x8*>(                             \
          smem + (HB) + (lg << 12) + (col << 4));                           \
    }                                                                       \
    _Pragma("unroll")                                                       \
    for (int m = 0; m < 2; ++m)                                             \
      _Pragma("unroll")                                                     \
      for (int n = 0; n < 4; ++n)                                           \
        acc[m][n] = __builtin_amdgcn_mfma_f32_16x16x32_bf16(af[m], bh[n],   \
                                                            acc[m][n], 0, 0, 0); \
  } while (0)

  // ---- prologue ----
  ISSUE_A(0);
  STAGE_H(0, HB0);
  VMWAIT0();
  CVTWR(AB0);
  PIPE_BARRIER();

  // ---- phase 1: 32 K-steps of 32, one lgkm-barrier per step ----
  for (int t2 = 0; t2 < 16; ++t2) {
    const int ke = (2 * t2 + 1) << 5;   // next-k for even step
    // even step t=2*t2: consume buf0, prefetch -> buf1 (t+1 <= 31 always)
    ISSUE_A(ke);
    STAGE_H(ke, HB1);
    CONS(AB0, HB0);
    VMWAIT0();
    CVTWR(AB1);
    PIPE_BARRIER();
    // odd step t=2*t2+1: consume buf1, prefetch -> buf0 (only if t < 31)
    if (t2 < 15) {
      const int ko = (2 * t2 + 2) << 5;
      ISSUE_A(ko);
      STAGE_H(ko, HB0);
      CONS(AB1, HB1);
      VMWAIT0();
      CVTWR(AB0);
      PIPE_BARRIER();
    } else {
      CONS(AB1, HB1);
    }
  }

  // ---- rowmax finalize (8 staging lanes per row are adjacent) ----
  {
    float v = pmax;
    v = fmaxf(v, __shfl_xor(v, 1));
    v = fmaxf(v, __shfl_xor(v, 2));
    v = fmaxf(v, __shfl_xor(v, 4));
    if ((tid & 7) == 0) smax[arow] = v;
  }
  __syncthreads();   // phase-1 LDS fully retired before aliasing

  // ---- write k tile (/3, bf16) -> Kld [32][512B] XOR ----
  {
    const float inv3 = 1.0f / 3.0f;
#pragma unroll
    for (int m = 0; m < 2; ++m)
#pragma unroll
      for (int n = 0; n < 4; ++n) {
        int col = wcol + (n << 4) + l15;
#pragma unroll
        for (int j = 0; j < 4; ++j) {
          int row = (m << 4) + (lg << 2) + j;
          *reinterpret_cast<unsigned short*>(smem + KLD + row * 512 +
                                             ((col * 2) ^ ((row & 7) << 4))) =
              f2bf(acc[m][n][j] * inv3);
        }
      }
  }
  __syncthreads();

  // ---- GEMM1: y[32][128] = k @ W1 (W1T fragments straight from L2) ----
  f32x4 acc1[2][2];
#pragma unroll
  for (int m = 0; m < 2; ++m)
#pragma unroll
    for (int n = 0; n < 2; ++n) acc1[m][n] = f32x4{0.f, 0.f, 0.f, 0.f};
  const int wcol1 = wid << 5;  // 0,32,64,96
#pragma unroll
  for (int kq = 0; kq < 8; ++kq) {
    bf16x8 af[2], bw[2];
#pragma unroll
    for (int m = 0; m < 2; ++m) {
      int row = (m << 4) + l15;
      af[m] = *reinterpret_cast<const bf16x8*>(smem + KLD + row * 512 +
              (((kq * 32 + (lg << 3)) * 2) ^ ((row & 7) << 4)));
    }
#pragma unroll
    for (int n = 0; n < 2; ++n) {
      int col = wcol1 + (n << 4) + l15;
      bw[n] = *reinterpret_cast<const bf16x8*>(W1Tg + (size_t)col * 256 +
                                               kq * 32 + (lg << 3));
    }
#pragma unroll
    for (int m = 0; m < 2; ++m)
#pragma unroll
      for (int n = 0; n < 2; ++n)
        acc1[m][n] = __builtin_amdgcn_mfma_f32_16x16x32_bf16(af[m], bw[n], acc1[m][n], 0, 0, 0);
  }
  __syncthreads();  // done reading Kld; Cld may overwrite

  // ---- c = relu(y+b1) -> Cld [32][256B] XOR (aliases Kld) ----
  {
#pragma unroll
    for (int n = 0; n < 2; ++n) {
      int col = wcol1 + (n << 4) + l15;
      float bias = b1g[col];
#pragma unroll
      for (int m = 0; m < 2; ++m)
#pragma unroll
        for (int j = 0; j < 4; ++j) {
          int row = (m << 4) + (lg << 2) + j;
          float v = fmaxf(acc1[m][n][j] + bias, 0.f);
          *reinterpret_cast<unsigned short*>(smem + CLD + row * 256 +
                                             ((col * 2) ^ ((row & 7) << 4))) = f2bf(v);
        }
    }
  }
  __syncthreads();

  // ---- GEMM2: out2[32][256] = c @ W2 (W2T fragments from L2) ----
  f32x4 acc2[2][4];
#pragma unroll
  for (int m = 0; m < 2; ++m)
#pragma unroll
    for (int n = 0; n < 4; ++n) acc2[m][n] = f32x4{0.f, 0.f, 0.f, 0.f};
#pragma unroll
  for (int kq = 0; kq < 4; ++kq) {
    bf16x8 af[2], bw[4];
#pragma unroll
    for (int m = 0; m < 2; ++m) {
      int row = (m << 4) + l15;
      af[m] = *reinterpret_cast<const bf16x8*>(smem + CLD + row * 256 +
              (((kq * 32 + (lg << 3)) * 2) ^ ((row & 7) << 4)));
    }
#pragma unroll
    for (int n = 0; n < 4; ++n) {
      int col = wcol + (n << 4) + l15;
      bw[n] = *reinterpret_cast<const bf16x8*>(W2Tg + (size_t)col * 128 +
                                               kq * 32 + (lg << 3));
    }
#pragma unroll
    for (int m = 0; m < 2; ++m)
#pragma unroll
      for (int n = 0; n < 4; ++n)
        acc2[m][n] = __builtin_amdgcn_mfma_f32_16x16x32_bf16(af[m], bw[n], acc2[m][n], 0, 0, 0);
  }

  // ---- epilogue: out = (out2+b2)*mask + h*(1-mask) ----
  {
#pragma unroll
    for (int n = 0; n < 4; ++n) {
      int col = wcol + (n << 4) + l15;
      float b2v = b2g[col];
#pragma unroll
      for (int m = 0; m < 2; ++m)
#pragma unroll
        for (int j = 0; j < 4; ++j) {
          int row = (m << 4) + (lg << 2) + j;
          float kv = acc2[m][n][j] + b2v;
          float mask = smax[row];
          size_t gidx = ((size_t)b * NN + r0 + row) * MM + col;
          float hv = hg[gidx];
          outg[gidx] = kv * mask + hv * (1.f - mask);
        }
    }
  }
#undef CONS
#undef CVTWR
#undef ISSUE_A
#undef STAGE_H
}

extern "C" void kernel_launch(void* const* d_in, const int* in_sizes, int n_in,
                              void* d_out, int out_size, void* d_ws, size_t ws_size,
                              hipStream_t stream) {
  (void)in_sizes; (void)n_in; (void)out_size; (void)ws_size;
  const float* A  = (const float*)d_in[0];
  const float* h  = (const float*)d_in[1];
  const float* W1 = (const float*)d_in[2];
  const float* b1 = (const float*)d_in[3];
  const float* W2 = (const float*)d_in[4];
  const float* b2 = (const float*)d_in[5];
  float* out = (float*)d_out;

  unsigned short* hT  = (unsigned short*)d_ws;
  unsigned short* W1T = (unsigned short*)((char*)d_ws + (size_t)BB * MM * NN * 2);
  unsigned short* W2T = W1T + MM * HH;

  k_transpose_h<<<BB * 64, 256, 0, stream>>>(h, hT);
  k_transpose_w<<<256, 256, 0, stream>>>(W1, W2, W1T, W2T);
  k_fused<<<BB * 32, 256, 0, stream>>>(A, h, hT, W1T, W2T, b1, b2, out);
}

// Round 9
// 107.041 us; speedup vs baseline: 1.1759x; 1.1759x over previous
//
#include <hip/hip_runtime.h>

typedef __attribute__((ext_vector_type(8))) short bf16x8;
typedef __attribute__((ext_vector_type(4))) float f32x4;
typedef __attribute__((ext_vector_type(8))) unsigned short u16x8;

#define BB 32
#define NN 1024
#define MM 256
#define HH 128

__device__ __forceinline__ unsigned short f2bf(float f) {
  union { float f; unsigned int u; } c; c.f = f;
  unsigned int u = c.u + 0x7fffu + ((c.u >> 16) & 1u);  // RNE
  return (unsigned short)(u >> 16);
}
__device__ __forceinline__ unsigned int cvtpk(float lo, float hi) {
  unsigned int r;
  asm("v_cvt_pk_bf16_f32 %0, %1, %2" : "=v"(r) : "v"(lo), "v"(hi));
  return r;
}
// volatile global load: fixed program position among volatiles
__device__ __forceinline__ float4 gload_f4(const float* p) {
  float4 r;
  asm volatile("global_load_dwordx4 %0, %1, off" : "=v"(r) : "v"(p));
  return r;
}
typedef __attribute__((address_space(3))) unsigned int as3_u32;
typedef const __attribute__((address_space(1))) unsigned int as1_u32;
__device__ __forceinline__ void gl_lds16(const void* g, void* l) {
  __builtin_amdgcn_global_load_lds((as1_u32*)g, (as3_u32*)l, 16, 0, 0);
}

// ---------- combined pre-pass: hT (bf16 [B][M][N]) + W1T/W2T ----------
__global__ __launch_bounds__(256)
void k_prep(const float* __restrict__ hg, unsigned short* __restrict__ hTg,
            const float* __restrict__ W1, const float* __restrict__ W2,
            unsigned short* __restrict__ W1T, unsigned short* __restrict__ W2T) {
  int bid = blockIdx.x;
  if (bid < BB * 64) {
    __shared__ unsigned short tile[64][65];
    int b = bid >> 6;
    int t = bid & 63;
    int k0 = (t >> 2) << 6;
    int m0 = (t & 3) << 6;
    int tt = threadIdx.x;
    {
      int r = tt >> 2;
      int cg = (tt & 3) << 4;
      const float* src = hg + (((size_t)b * NN + k0 + r) * MM + m0 + cg);
#pragma unroll
      for (int i = 0; i < 4; ++i) {
        float4 v = reinterpret_cast<const float4*>(src)[i];
        tile[r][cg + i * 4 + 0] = f2bf(v.x);
        tile[r][cg + i * 4 + 1] = f2bf(v.y);
        tile[r][cg + i * 4 + 2] = f2bf(v.z);
        tile[r][cg + i * 4 + 3] = f2bf(v.w);
      }
    }
    __syncthreads();
    {
      int mr = tt >> 2;
      int kc = (tt & 3) << 4;
      alignas(16) unsigned short tmp[16];
#pragma unroll
      for (int i = 0; i < 16; ++i) tmp[i] = tile[kc + i][mr];
      unsigned short* dst = hTg + (((size_t)b * MM + m0 + mr) * NN + k0 + kc);
      *reinterpret_cast<u16x8*>(dst)     = *reinterpret_cast<u16x8*>(tmp);
      *reinterpret_cast<u16x8*>(dst + 8) = *reinterpret_cast<u16x8*>(tmp + 8);
    }
  } else {
    int idx = (bid - BB * 64) * 256 + threadIdx.x;
    if (idx < MM * HH) {
      int hc = idx >> 8;
      int m  = idx & 255;
      W1T[idx] = f2bf(W1[m * HH + hc]);
    } else {
      int j = idx - MM * HH;
      int m  = j >> 7;
      int hd = j & 127;
      W2T[j] = f2bf(W2[hd * MM + m]);
    }
  }
}

// ---------------- fused main ----------------
// 512 blocks x 512 threads (8 waves = 4 row-groups x 2 col-halves).
// Block tile 64 rows x 256 cols; per wave 16r x 128c (1m x 8n), BK=32.
// Phase 1 (32 K-steps): A fp32 direct->reg (asm volatile, 1 step ahead,
// loads live ACROSS the barrier via counted vmcnt); H staged via
// global_load_lds into subtiled LDS [coltile][lg][col16] (contiguous 1KB
// wave reads, linear gl_lds dest, coalesced source). Per step:
//   vmcnt(0) [A(t) regs - issued a full step ago] ; cvt+rowmax
//   issue H(t+1) gl_lds x2 ; issue A(t+1) x2
//   8 x {ds_read_b128 ; MFMA}
//   vmcnt(2) [H(t+1) in LDS, A(t+1) STILL IN FLIGHT] ; s_barrier
// LDS: H dbuf 2x16KB; Kld[64][512B] aliases both bufs; Cld[64][256B] aliases.
#define HB0 0
#define HB1 16384
#define KLD 0
#define CLD 0

__global__ __launch_bounds__(512, 4)
void k_fused(const float* __restrict__ Ag, const float* __restrict__ hg,
             const unsigned short* __restrict__ hTg,
             const unsigned short* __restrict__ W1Tg,
             const unsigned short* __restrict__ W2Tg,
             const float* __restrict__ b1g, const float* __restrict__ b2g,
             float* __restrict__ outg) {
  __shared__ __align__(16) char smem[32768];
  __shared__ float smax[64];

  const int tid  = threadIdx.x;
  const int lane = tid & 63;
  const int wid  = tid >> 6;       // 0..7
  const int wr   = wid >> 1;       // 0..3 row group (16 rows)
  const int wc   = wid & 1;        // 0..1 col half (128 cols)
  const int l15  = lane & 15;
  const int lg   = lane >> 4;      // 0..3

  const int bid = blockIdx.x;
  const int b   = bid & 31;        // batch-b blocks share bid%8 -> same XCD L2
  const int r0  = (bid >> 5) << 6; // 16 row-blocks of 64

  const float* Ab = Ag + ((size_t)b * NN + r0) * NN;
  const unsigned short* hTb = hTg + (size_t)b * MM * NN;

  // A: lane(l15,lg) owns row wr*16+l15, k-slice lg*8..+7 of each 32-k step
  const int arow = (wr << 4) + l15;
  const float* Asrc = Ab + (size_t)arow * NN + (lg << 3);

  // H staging: chunk c = i*512+tid -> (coltile=c>>6, lgc=(c>>4)&3, c16=c&15)
  const unsigned short* baseH[2];
  {
    int c0 = tid;
    baseH[0] = hTb + (size_t)(((c0 >> 6) << 4) + (c0 & 15)) * NN + (((c0 >> 4) & 3) << 3);
    int c1 = tid + 512;
    baseH[1] = hTb + (size_t)(((c1 >> 6) << 4) + (c1 & 15)) * NN + (((c1 >> 4) & 3) << 3);
  }
  // wave-uniform LDS dest bases (HW adds lane*16)
  const int dstW = wid << 10;

#define STAGE_H(K0, HB)                                                      \
  do {                                                                       \
    gl_lds16(baseH[0] + (K0), smem + (HB) + dstW);                           \
    gl_lds16(baseH[1] + (K0), smem + (HB) + 8192 + dstW);                    \
  } while (0)

  float4 rA0, rA1;
#define ISSUE_A(K0)                                                          \
  do {                                                                       \
    rA0 = gload_f4(Asrc + (K0));                                             \
    rA1 = gload_f4(Asrc + (K0) + 4);                                         \
  } while (0)

  float pmax = -1e30f;
  bf16x8 af;
#define CVT_A()                                                              \
  do {                                                                       \
    pmax = fmaxf(pmax, fmaxf(fmaxf(fmaxf(rA0.x, rA0.y), fmaxf(rA0.z, rA0.w)),\
                             fmaxf(fmaxf(rA1.x, rA1.y), fmaxf(rA1.z, rA1.w))));\
    uint4 q = make_uint4(cvtpk(rA0.x, rA0.y), cvtpk(rA0.z, rA0.w),           \
                         cvtpk(rA1.x, rA1.y), cvtpk(rA1.z, rA1.w));          \
    af = *reinterpret_cast<bf16x8*>(&q);                                     \
  } while (0)

  f32x4 acc[8];
#pragma unroll
  for (int n = 0; n < 8; ++n) acc[n] = f32x4{0.f, 0.f, 0.f, 0.f};

  // per-thread bh base: subtile layout (wc*8+n)*1024 + lg*256 + l15*16
  const char* bhBase = smem + (wc << 13) + (lg << 8) + (l15 << 4);

#define MFMA_STEP(HB)                                                        \
  do {                                                                       \
    bf16x8 bh[8];                                                            \
    _Pragma("unroll")                                                        \
    for (int n = 0; n < 8; ++n)                                              \
      bh[n] = *reinterpret_cast<const bf16x8*>(bhBase + (HB) + n * 1024);    \
    _Pragma("unroll")                                                        \
    for (int n = 0; n < 8; ++n)                                              \
      acc[n] = __builtin_amdgcn_mfma_f32_16x16x32_bf16(af, bh[n], acc[n], 0, 0, 0); \
  } while (0)

#define VMW0() do { asm volatile("s_waitcnt vmcnt(0)" ::: "memory"); \
  __builtin_amdgcn_sched_barrier(0); } while (0)
#define VMW2() do { asm volatile("s_waitcnt vmcnt(2)" ::: "memory"); \
  __builtin_amdgcn_sched_barrier(0); } while (0)

  // ---- prologue: stage step 0 (H first, A second), wait H only ----
  STAGE_H(0, HB0);
  ISSUE_A(0);
  VMW2();
  __builtin_amdgcn_s_barrier();

  // ---- phase 1: 32 K-steps of 32 ----
#pragma unroll
  for (int t = 0; t < 32; ++t) {
    VMW0();                       // A(t) regs landed (issued a full step ago)
    CVT_A();
    if (t < 31) {
      STAGE_H((t + 1) * 32, (t & 1) ? HB0 : HB1);  // H first
      ISSUE_A((t + 1) * 32);                       // A second (stays in flight)
    }
    MFMA_STEP((t & 1) ? HB1 : HB0);
    if (t < 31) {
      VMW2();                     // H(t+1) in LDS; A(t+1) still flying
      __builtin_amdgcn_s_barrier();
    }
  }

  // ---- rowmax finalize: reduce lg-slices; wc==0 waves write ----
  {
    float v = pmax;
    v = fmaxf(v, __shfl_xor(v, 16));
    v = fmaxf(v, __shfl_xor(v, 32));
    if (wc == 0 && lg == 0) smax[arow] = v;
  }
  __syncthreads();   // phase-1 LDS retired before aliasing

  // ---- write k tile (/3, bf16) -> Kld [64][512B] XOR ----
  {
    const float inv3 = 1.0f / 3.0f;
#pragma unroll
    for (int n = 0; n < 8; ++n) {
      int col = (wc << 7) + (n << 4) + l15;
#pragma unroll
      for (int j = 0; j < 4; ++j) {
        int row = (wr << 4) + (lg << 2) + j;
        *reinterpret_cast<unsigned short*>(smem + KLD + row * 512 +
                                           ((col * 2) ^ ((row & 7) << 4))) =
            f2bf(acc[n][j] * inv3);
      }
    }
  }
  __syncthreads();

  // ---- GEMM1: y[64][128] = k @ W1 (W1T frags from L2) ----
  f32x4 acc1[4];
#pragma unroll
  for (int n = 0; n < 4; ++n) acc1[n] = f32x4{0.f, 0.f, 0.f, 0.f};
  const int wcol1 = wc << 6;  // 0,64
#pragma unroll
  for (int kq = 0; kq < 8; ++kq) {
    int row = (wr << 4) + l15;
    bf16x8 a1 = *reinterpret_cast<const bf16x8*>(smem + KLD + row * 512 +
                (((kq << 6) + (lg << 4)) ^ ((row & 7) << 4)));
    bf16x8 bw[4];
#pragma unroll
    for (int n = 0; n < 4; ++n) {
      int col = wcol1 + (n << 4) + l15;
      bw[n] = *reinterpret_cast<const bf16x8*>(W1Tg + (size_t)col * 256 +
                                               (kq << 5) + (lg << 3));
    }
#pragma unroll
    for (int n = 0; n < 4; ++n)
      acc1[n] = __builtin_amdgcn_mfma_f32_16x16x32_bf16(a1, bw[n], acc1[n], 0, 0, 0);
  }
  __syncthreads();  // Kld fully read; Cld may overwrite

  // ---- c = relu(y+b1) -> Cld [64][256B] XOR ----
  {
#pragma unroll
    for (int n = 0; n < 4; ++n) {
      int col = wcol1 + (n << 4) + l15;
      float bias = b1g[col];
#pragma unroll
      for (int j = 0; j < 4; ++j) {
        int row = (wr << 4) + (lg << 2) + j;
        float v = fmaxf(acc1[n][j] + bias, 0.f);
        *reinterpret_cast<unsigned short*>(smem + CLD + row * 256 +
                                           ((col * 2) ^ ((row & 7) << 4))) = f2bf(v);
      }
    }
  }
  __syncthreads();

  // ---- GEMM2: out2[64][256] = c @ W2 (W2T frags from L2) ----
  f32x4 acc2[8];
#pragma unroll
  for (int n = 0; n < 8; ++n) acc2[n] = f32x4{0.f, 0.f, 0.f, 0.f};
#pragma unroll
  for (int kq = 0; kq < 4; ++kq) {
    int row = (wr << 4) + l15;
    bf16x8 a2 = *reinterpret_cast<const bf16x8*>(smem + CLD + row * 256 +
                (((kq << 6) + (lg << 4)) ^ ((row & 7) << 4)));
    bf16x8 bw[8];
#pragma unroll
    for (int n = 0; n < 8; ++n) {
      int col = (wc << 7) + (n << 4) + l15;
      bw[n] = *reinterpret_cast<const bf16x8*>(W2Tg + (size_t)col * 128 +
                                               (kq << 5) + (lg << 3));
    }
#pragma unroll
    for (int n = 0; n < 8; ++n)
      acc2[n] = __builtin_amdgcn_mfma_f32_16x16x32_bf16(a2, bw[n], acc2[n], 0, 0, 0);
  }

  // ---- epilogue: out = (out2+b2)*mask + h*(1-mask) ----
  {
#pragma unroll
    for (int n = 0; n < 8; ++n) {
      int col = (wc << 7) + (n << 4) + l15;
      float b2v = b2g[col];
#pragma unroll
      for (int j = 0; j < 4; ++j) {
        int row = (wr << 4) + (lg << 2) + j;
        float kv = acc2[n][j] + b2v;
        float mask = smax[row];
        size_t gidx = ((size_t)b * NN + r0 + row) * MM + col;
        float hv = hg[gidx];
        outg[gidx] = kv * mask + hv * (1.f - mask);
      }
    }
  }
#undef MFMA_STEP
#undef CVT_A
#undef ISSUE_A
#undef STAGE_H
#undef VMW0
#undef VMW2
}

extern "C" void kernel_launch(void* const* d_in, const int* in_sizes, int n_in,
                              void* d_out, int out_size, void* d_ws, size_t ws_size,
                              hipStream_t stream) {
  (void)in_sizes; (void)n_in; (void)out_size; (void)ws_size;
  const float* A  = (const float*)d_in[0];
  const float* h  = (const float*)d_in[1];
  const float* W1 = (const float*)d_in[2];
  const float* b1 = (const float*)d_in[3];
  const float* W2 = (const float*)d_in[4];
  const float* b2 = (const float*)d_in[5];
  float* out = (float*)d_out;

  unsigned short* hT  = (unsigned short*)d_ws;
  unsigned short* W1T = (unsigned short*)((char*)d_ws + (size_t)BB * MM * NN * 2);
  unsigned short* W2T = W1T + MM * HH;

  k_prep<<<BB * 64 + 256, 256, 0, stream>>>(h, hT, W1, W2, W1T, W2T);
  k_fused<<<BB * 16, 512, 0, stream>>>(A, h, hT, W1T, W2T, b1, b2, out);
}